// Round 1
// 706.976 us; speedup vs baseline: 1.4048x; 1.4048x over previous
//
#include <hip/hip_runtime.h>
#include <hip/hip_bf16.h>

#define L_DIM  1024
#define N_DIM  64
#define IN_DIM 1024
#define OUT_DIM 1024

#define BM 128          // l rows per GEMM block
#define BN 128          // o cols per GEMM block
#define BK 64           // K step (bf16 elems)
#define LDK 72          // padded stride for fallback kernel only

typedef __attribute__((ext_vector_type(8))) short  short8;   // 8 x bf16 MFMA frag
typedef __attribute__((ext_vector_type(4))) float  f32x4;    // MFMA accumulator
typedef __attribute__((ext_vector_type(8))) unsigned short ushort8;

static __device__ __forceinline__ unsigned short f2b(float f) {
  __hip_bfloat16 h = __float2bfloat16(f);   // RNE
  return __builtin_bit_cast(unsigned short, h);
}

// async global->LDS, 16B per lane; LDS dest = wave-uniform base + lane*16
static __device__ __forceinline__ void gload_lds16(const void* g, void* l) {
  __builtin_amdgcn_global_load_lds((const __attribute__((address_space(1))) void*)g,
                                   (__attribute__((address_space(3))) void*)l,
                                   16, 0, 0);
}

// ---------------- Pass 0: fp32 -> bf16 convert (spk and W) ---------------------------
__global__ __launch_bounds__(256)
void cvt_kernel(const float* __restrict__ src, unsigned short* __restrict__ dst, int nvec) {
  const int stride = gridDim.x * 256;
  for (int i = blockIdx.x * 256 + threadIdx.x; i < nvec; i += stride) {
    const float4 a = *reinterpret_cast<const float4*>(src + (size_t)i * 8);
    const float4 b = *reinterpret_cast<const float4*>(src + (size_t)i * 8 + 4);
    ushort8 u;
    u[0] = f2b(a.x); u[1] = f2b(a.y); u[2] = f2b(a.z); u[3] = f2b(a.w);
    u[4] = f2b(b.x); u[5] = f2b(b.y); u[6] = f2b(b.z); u[7] = f2b(b.w);
    *reinterpret_cast<ushort8*>(dst + (size_t)i * 8) = u;
  }
}

// ---------------- Pass 1 (new): bf16 GEMM, global_load_lds staging (m97 recipe) ------
// cur[l,n,o] = spk[l,n,:] @ W[o,:]^T + b[o], fp32 out.
// grid (n=64, ot=8, lch=8): id%8 == n%8 -> blocks sharing the A-panel land on one XCD.
__global__ __launch_bounds__(256, 4)
void gemm_bf16(const unsigned short* __restrict__ A,   // spk bf16 [l,n,k]
               const unsigned short* __restrict__ B,   // W bf16 [o,k]
               const float* __restrict__ bias, float* __restrict__ out) {
  __shared__ unsigned short As[BM * BK];   // linear, unpadded (global_load_lds requirement)
  __shared__ unsigned short Bs[BN * BK];
  const int tid  = threadIdx.x;
  const int n    = blockIdx.x;
  const int ob   = blockIdx.y * BN;
  const int lb   = blockIdx.z * BM;
  const int wave = tid >> 6;
  const int lane = tid & 63;
  const int quad = lane >> 4;
  const int l15  = lane & 15;
  const int arow = (wave >> 1) * 64;     // wave row (l) base in 128x128 tile
  const int bcol = (wave & 1) * 64;      // wave col (o) base
  const int srow = lane >> 3;            // staging: row within 8-row group
  const int scol = (lane & 7) * 8;       // staging: bf16 col (16B per lane)

  // per-lane global element bases for staging (k0 added per step)
  const size_t abase = ((size_t)(lb + wave * 32 + srow) * N_DIM + n) * IN_DIM + scol;
  const size_t bbase = (size_t)(ob + wave * 32 + srow) * IN_DIM + scol;

  f32x4 acc[4][4];
#pragma unroll
  for (int t = 0; t < 4; ++t) {
    const float bv = bias[ob + bcol + t * 16 + l15];
    const f32x4 binit = {bv, bv, bv, bv};
#pragma unroll
    for (int m = 0; m < 4; ++m) acc[m][t] = binit;
  }

  for (int k0 = 0; k0 < IN_DIM; k0 += BK) {
    __syncthreads();   // previous compute done before overwriting LDS
#pragma unroll
    for (int t = 0; t < 4; ++t) {
      // each instr: 64 lanes x 16B = 8 rows x 128B, rows wave*32+8t .. +7
      gload_lds16(A + abase + (size_t)(8 * t) * N_DIM * IN_DIM + k0,
                  &As[(wave * 32 + 8 * t) * BK]);
      gload_lds16(B + bbase + (size_t)(8 * t) * IN_DIM + k0,
                  &Bs[(wave * 32 + 8 * t) * BK]);
    }
    __syncthreads();   // compiler drains vmcnt before barrier
#pragma unroll
    for (int kk = 0; kk < BK; kk += 32) {
      short8 av[4], bv[4];
#pragma unroll
      for (int m = 0; m < 4; ++m)
        av[m] = *reinterpret_cast<const short8*>(&As[(arow + m * 16 + l15) * BK + kk + quad * 8]);
#pragma unroll
      for (int t = 0; t < 4; ++t)
        bv[t] = *reinterpret_cast<const short8*>(&Bs[(bcol + t * 16 + l15) * BK + kk + quad * 8]);
#pragma unroll
      for (int m = 0; m < 4; ++m)
#pragma unroll
        for (int t = 0; t < 4; ++t)
          acc[m][t] = __builtin_amdgcn_mfma_f32_16x16x32_bf16(av[m], bv[t], acc[m][t], 0, 0, 0);
    }
  }
  // epilogue: C/D mapping col=lane&15, row=(lane>>4)*4+reg (verified)
#pragma unroll
  for (int m = 0; m < 4; ++m) {
#pragma unroll
    for (int t = 0; t < 4; ++t) {
      const int col = ob + bcol + t * 16 + l15;
#pragma unroll
      for (int j = 0; j < 4; ++j) {
        const int row = lb + arow + m * 16 + quad * 4 + j;
        out[(size_t)(row * N_DIM + n) * OUT_DIM + col] = acc[m][t][j];
      }
    }
  }
}

// ---------------- Pass 1 (fallback, ws too small): fused-convert fp32 GEMM ----------
__global__ __launch_bounds__(256, 4)
void gemm_kernel(const float* __restrict__ spk, const float* __restrict__ W,
                 const float* __restrict__ bias, float* __restrict__ out) {
  __shared__ unsigned short As[BM][LDK];
  __shared__ unsigned short Bs[BN][LDK];
  const int tid  = threadIdx.x;
  const int n    = blockIdx.x;
  const int ob   = blockIdx.y * BN;
  const int lb   = blockIdx.z * BM;
  const int wave = tid >> 6;
  const int lane = tid & 63;
  const int quad = lane >> 4;
  const int l15  = lane & 15;
  const int arow = (wave >> 1) * 64;
  const int bcol = (wave & 1) * 64;

  f32x4 acc[4][4];
#pragma unroll
  for (int t = 0; t < 4; ++t) {
    const float bv = bias[ob + bcol + t * 16 + l15];
    const f32x4 binit = {bv, bv, bv, bv};
#pragma unroll
    for (int m = 0; m < 4; ++m) acc[m][t] = binit;
  }

  for (int ks = 0; ks < IN_DIM / BK; ++ks) {
    const int k0 = ks * BK;
    __syncthreads();
#pragma unroll
    for (int j = 0; j < 8; ++j) {
      const int f = j * 256 + tid;
      const int r = f >> 4;
      const int c = (f & 15) << 2;
      const float4 v = *reinterpret_cast<const float4*>(
          spk + (size_t)((lb + r) * N_DIM + n) * IN_DIM + k0 + c);
      ushort4 u;
      u.x = f2b(v.x); u.y = f2b(v.y); u.z = f2b(v.z); u.w = f2b(v.w);
      *reinterpret_cast<ushort4*>(&As[r][c]) = u;
    }
#pragma unroll
    for (int j = 0; j < 8; ++j) {
      const int f = j * 256 + tid;
      const int r = f >> 4;
      const int c = (f & 15) << 2;
      const float4 v = *reinterpret_cast<const float4*>(
          W + (size_t)(ob + r) * IN_DIM + k0 + c);
      ushort4 u;
      u.x = f2b(v.x); u.y = f2b(v.y); u.z = f2b(v.z); u.w = f2b(v.w);
      *reinterpret_cast<ushort4*>(&Bs[r][c]) = u;
    }
    __syncthreads();
#pragma unroll
    for (int kk = 0; kk < BK; kk += 32) {
      short8 av[4], bv[4];
#pragma unroll
      for (int m = 0; m < 4; ++m)
        av[m] = *reinterpret_cast<const short8*>(&As[arow + m * 16 + l15][kk + quad * 8]);
#pragma unroll
      for (int t = 0; t < 4; ++t)
        bv[t] = *reinterpret_cast<const short8*>(&Bs[bcol + t * 16 + l15][kk + quad * 8]);
#pragma unroll
      for (int m = 0; m < 4; ++m)
#pragma unroll
        for (int t = 0; t < 4; ++t)
          acc[m][t] = __builtin_amdgcn_mfma_f32_16x16x32_bf16(av[m], bv[t], acc[m][t], 0, 0, 0);
    }
  }
#pragma unroll
  for (int m = 0; m < 4; ++m) {
#pragma unroll
    for (int t = 0; t < 4; ++t) {
      const int col = ob + bcol + t * 16 + l15;
#pragma unroll
      for (int j = 0; j < 4; ++j) {
        const int row = lb + arow + m * 16 + quad * 4 + j;
        out[(size_t)(row * N_DIM + n) * OUT_DIM + col] = acc[m][t][j];
      }
    }
  }
}

// ---------------- Pass 2: diagonal scan along l, 3-buffer pipeline ------------------
// mem = beta*mem + cur. One thread per (n,o). Loads run 3 chunks (48 planes) ahead of
// the serial FMA+store stream; src/dst may be the same buffer (in-place) — each plane
// is read once then written once, and the store's value depends on the read, so no
// reorder hazard.
#define U 16
__global__ __launch_bounds__(256)
void scan_kernel(const float* __restrict__ src, float* __restrict__ dst,
                 const float* __restrict__ mem_in, const float* __restrict__ beta) {
  const int n = blockIdx.x;
  const int o = blockIdx.y * 256 + threadIdx.x;
  float mem = mem_in[n * OUT_DIM + o];
  const float bt = beta[o];
  const size_t base = (size_t)n * OUT_DIM + o;
  const size_t ls = (size_t)N_DIM * OUT_DIM;

  float Ab[U], Bb[U], Cb[U];
#pragma unroll
  for (int j = 0; j < U; ++j) Ab[j] = src[base + (size_t)(0 * U + j) * ls];
#pragma unroll
  for (int j = 0; j < U; ++j) Bb[j] = src[base + (size_t)(1 * U + j) * ls];
#pragma unroll
  for (int j = 0; j < U; ++j) Cb[j] = src[base + (size_t)(2 * U + j) * ls];

#define SCAN_COMPUTE(BUF, CC)                                                  \
  _Pragma("unroll")                                                            \
  for (int j = 0; j < U; ++j) {                                                \
    mem = bt * mem + BUF[j];                                                   \
    dst[base + (size_t)((CC) * U + j) * ls] = mem;                             \
  }
#define SCAN_LOAD(BUF, CC)                                                     \
  _Pragma("unroll")                                                            \
  for (int j = 0; j < U; ++j) BUF[j] = src[base + (size_t)((CC) * U + j) * ls];

  int c = 0;
  for (; c + 5 < L_DIM / U; c += 3) {     // c = 0,3,...,57
    SCAN_COMPUTE(Ab, c);     SCAN_LOAD(Ab, c + 3);
    SCAN_COMPUTE(Bb, c + 1); SCAN_LOAD(Bb, c + 4);
    SCAN_COMPUTE(Cb, c + 2); SCAN_LOAD(Cb, c + 5);
  }
  // c == 60: chunks 60,61,62 resident in Ab,Bb,Cb; 63 not yet loaded
  SCAN_COMPUTE(Ab, 60); SCAN_LOAD(Ab, 63);
  SCAN_COMPUTE(Bb, 61);
  SCAN_COMPUTE(Cb, 62);
  SCAN_COMPUTE(Ab, 63);

  // final_mem appended after out_seq
  dst[(size_t)L_DIM * N_DIM * OUT_DIM + (size_t)n * OUT_DIM + o] = mem;
}

extern "C" void kernel_launch(void* const* d_in, const int* in_sizes, int n_in,
                              void* d_out, int out_size, void* d_ws, size_t ws_size,
                              hipStream_t stream) {
  const float* spk  = (const float*)d_in[0];
  const float* mem  = (const float*)d_in[1];
  const float* W    = (const float*)d_in[2];
  const float* bias = (const float*)d_in[3];
  const float* beta = (const float*)d_in[4];
  float* out = (float*)d_out;

  const size_t CUR_BYTES  = (size_t)L_DIM * N_DIM * OUT_DIM * 4;  // 256 MiB
  const size_t SPKB_BYTES = (size_t)L_DIM * N_DIM * IN_DIM * 2;   // 128 MiB
  const size_t WB_BYTES   = (size_t)OUT_DIM * IN_DIM * 2;         //   2 MiB
  char* ws = (char*)d_ws;
  const bool haveCvt = (ws != nullptr) && (ws_size >= SPKB_BYTES + WB_BYTES);
  const bool haveCur = (ws != nullptr) && (ws_size >= CUR_BYTES + SPKB_BYTES + WB_BYTES);

  if (haveCvt) {
    float* cur;
    unsigned short* spkb;
    unsigned short* wb;
    if (haveCur) {               // full plan: out-of-place scan
      cur  = (float*)ws;
      spkb = (unsigned short*)(ws + CUR_BYTES);
      wb   = (unsigned short*)(ws + CUR_BYTES + SPKB_BYTES);
    } else {                     // mid plan: bf16 gemm, in-place scan
      cur  = out;
      spkb = (unsigned short*)ws;
      wb   = (unsigned short*)(ws + SPKB_BYTES);
    }
    cvt_kernel<<<dim3(2048), dim3(256), 0, stream>>>(spk, spkb, L_DIM * N_DIM * IN_DIM / 8);
    cvt_kernel<<<dim3(512),  dim3(256), 0, stream>>>(W,   wb,   OUT_DIM * IN_DIM / 8);

    dim3 g1(N_DIM, OUT_DIM / BN, L_DIM / BM);   // (64, 8, 8)
    gemm_bf16<<<g1, dim3(256), 0, stream>>>(spkb, wb, bias, cur);

    dim3 g2(N_DIM, OUT_DIM / 256);              // (64, 4)
    scan_kernel<<<g2, dim3(256), 0, stream>>>(cur, out, mem, beta);
  } else {                       // fallback: previous-session path
    dim3 g1(N_DIM, OUT_DIM / BN, L_DIM / BM);
    gemm_kernel<<<g1, dim3(256), 0, stream>>>(spk, W, bias, out);
    dim3 g2(N_DIM, OUT_DIM / 256);
    scan_kernel<<<g2, dim3(256), 0, stream>>>(out, out, mem, beta);
  }
}